// Round 18
// baseline (91.384 us; speedup 1.0000x reference)
//
#include <hip/hip_runtime.h>
#include <math.h>

// ComplexGaussianRasterizer — home-bucket bin + fused pull-scan voxel-gather,
// candidate-pair eval with component-major LDS staging and FORCED v_pk_* ops.
// 3 nodes:
//   memset:  zero homecnt (128 KB).
//   K1 build: per gaussian -> 48B record at rec[g] (coalesced); append
//             (pb, id) to its 4^3 home cell's fixed-HCAP bucket (1 atomic).
//   K2 eval:  one wave per 4^3 subtile, one voxel per lane. Wave pulls the 27
//             neighbor homes' (pb,id) slots, window-tests, ballot-compacts ids
//             into wave-private LDS. Component-major staging (zero conflicts);
//             float4 read at c*64+4t serves 4 candidates. Quadratic for each
//             pair in inline-asm v_pk_fma_f32/v_pk_mul_f32 (guaranteed VOP3P);
//             in-test via readfirstlane + SALU unpack + v_sub x3 + v_max3.

#define RES    128
#define NSBA   32
#define NTILE  (NSBA * NSBA * NSBA)   // 32768 home cells
#define RECSZ  12                     // floats per record (48 B)
#define HCAP   20                     // home-bucket capacity (lambda ~3.05)
#define CAP    96                     // per-subtile candidate cap (lambda ~35)

typedef float f32x2 __attribute__((ext_vector_type(2)));

__device__ __forceinline__ f32x2 pk_fma(f32x2 a, f32x2 b, f32x2 c) {
    f32x2 d;
    asm("v_pk_fma_f32 %0, %1, %2, %3" : "=v"(d) : "v"(a), "v"(b), "v"(c));
    return d;
}
__device__ __forceinline__ f32x2 pk_mul(f32x2 a, f32x2 b) {
    f32x2 d;
    asm("v_pk_mul_f32 %0, %1, %2" : "=v"(d) : "v"(a), "v"(b));
    return d;
}

// ---------------- record builder (quad coeffs scaled by log2e) -------------
__device__ __forceinline__ void build_record_at(
    const float* means, const float* opacities, const float* scales,
    const float* rotations, const float* phases, const float* phases_add,
    float* recdst, int g, int* bxo, int* byo, int* bzo)
{
    const float LB   = -1.0f;
    const float VOX  = 2.0f / 128.0f;
    const float L2E  = 1.4426950408889634f;

    float mx = means[g*3+0], my = means[g*3+1], mz = means[g*3+2];
    float op = opacities[g];
    float sx = scales[g*3+0], sy = scales[g*3+1], sz = scales[g*3+2];
    float qw = rotations[g*4+0], qx = rotations[g*4+1],
          qy = rotations[g*4+2], qz = rotations[g*4+3];
    float ph = phases[g], pa = phases_add[g];

    float qn = rsqrtf(qw*qw + qx*qx + qy*qy + qz*qz);
    qw *= qn; qx *= qn; qy *= qn; qz *= qn;

    float r00 = 1.0f - 2.0f*(qy*qy + qz*qz);
    float r01 = 2.0f*(qx*qy - qw*qz);
    float r02 = 2.0f*(qx*qz + qw*qy);
    float r10 = 2.0f*(qx*qy + qw*qz);
    float r11 = 1.0f - 2.0f*(qx*qx + qz*qz);
    float r12 = 2.0f*(qy*qz - qw*qx);
    float r20 = 2.0f*(qx*qz - qw*qy);
    float r21 = 2.0f*(qy*qz + qw*qx);
    float r22 = 1.0f - 2.0f*(qx*qx + qy*qy);

    float m00 = r00*sx, m01 = r01*sy, m02 = r02*sz;
    float m10 = r10*sx, m11 = r11*sy, m12 = r12*sz;
    float m20 = r20*sx, m21 = r21*sy, m22 = r22*sz;

    float a = m00*m00 + m01*m01 + m02*m02;
    float b = m00*m10 + m01*m11 + m02*m12;
    float c = m00*m20 + m01*m21 + m02*m22;
    float d = m10*m10 + m11*m11 + m12*m12;
    float e = m10*m20 + m11*m21 + m12*m22;
    float f = m20*m20 + m21*m21 + m22*m22;

    float A = d*f - e*e;
    float B = c*e - b*f;
    float C = b*e - c*d;
    float det  = a*A + b*B + c*C;
    float idet = L2E / det;            // fold log2e into all quad coeffs

    float n00 = -0.5f * A * idet;
    float n01 = -B * idet;
    float n02 = -C * idet;
    float n11 = -0.5f * (a*f - c*c) * idet;
    float n12 = -(b*c - a*e) * idet;
    float n22 = -0.5f * (a*d - b*b) * idet;

    int bx = (int)floorf((mx - LB) * 64.0f) - 3;
    int by = (int)floorf((my - LB) * 64.0f) - 3;
    int bz = (int)floorf((mz - LB) * 64.0f) - 3;
    unsigned pb = ((unsigned)(bx + 4) << 16) | ((unsigned)(by + 4) << 8) |
                  (unsigned)(bz + 4);

    float sr, cr;
    __sincosf(ph, &sr, &cr);
    float wr = op * cr;
    float wi = op * (sr + pa);

    float fx = LB + 0.5f * VOX - mx;
    float fy = LB + 0.5f * VOX - my;
    float fz = LB + 0.5f * VOX - mz;

    float4* rp = reinterpret_cast<float4*>(recdst);
    rp[0] = make_float4(n00, n01, n02, n11);
    rp[1] = make_float4(n12, n22, fx, fy);
    rp[2] = make_float4(fz, wr, wi, __uint_as_float(pb));
    *bxo = bx; *byo = by; *bzo = bz;
}

// ---------------- K1: build records + home-bucket append ----------------
__global__ __launch_bounds__(256) void cgr_build(
    const float* __restrict__ means, const float* __restrict__ opacities,
    const float* __restrict__ scales, const float* __restrict__ rotations,
    const float* __restrict__ phases, const float* __restrict__ phases_add,
    float* __restrict__ rec, int* __restrict__ homecnt,
    unsigned* __restrict__ hpb, int* __restrict__ hlist, int N)
{
    int g = blockIdx.x * 256 + threadIdx.x;
    if (g >= N) return;
    int bx, by, bz;
    build_record_at(means, opacities, scales, rotations, phases, phases_add,
                    rec + (size_t)g * RECSZ, g, &bx, &by, &bz);
    unsigned pb = ((unsigned)(bx + 4) << 16) | ((unsigned)(by + 4) << 8) |
                  (unsigned)(bz + 4);
    int hx = min(max(bx, 0), RES - 1) >> 2;
    int hy = min(max(by, 0), RES - 1) >> 2;
    int hz = min(max(bz, 0), RES - 1) >> 2;
    int h = (hx * NSBA + hy) * NSBA + hz;
    int slot = atomicAdd(&homecnt[h], 1);
    if (slot < HCAP) {
        hpb[h * HCAP + slot]   = pb;
        hlist[h * HCAP + slot] = g;
    }
}

// evaluate one candidate pair from component float4s (S0/S1 select the pair)
#define EVAL_PAIR(S0, S1)                                                     \
    do {                                                                      \
        f32x2 pn00 = {c_n00.S0, c_n00.S1};                                    \
        f32x2 pn01 = {c_n01.S0, c_n01.S1};                                    \
        f32x2 pn02 = {c_n02.S0, c_n02.S1};                                    \
        f32x2 pn11 = {c_n11.S0, c_n11.S1};                                    \
        f32x2 pn12 = {c_n12.S0, c_n12.S1};                                    \
        f32x2 pn22 = {c_n22.S0, c_n22.S1};                                    \
        f32x2 pfx  = {c_fx.S0,  c_fx.S1};                                     \
        f32x2 pfy  = {c_fy.S0,  c_fy.S1};                                     \
        f32x2 pfz  = {c_fz.S0,  c_fz.S1};                                     \
        f32x2 dxp = pk_fma(fvx2, voxc2, pfx);                                 \
        f32x2 dyp = pk_fma(fvy2, voxc2, pfy);                                 \
        f32x2 dzp = pk_fma(fvz2, voxc2, pfz);                                 \
        f32x2 t0 = pk_fma(pn01, dyp, pk_mul(pn00, dxp));                      \
        t0 = pk_fma(pn02, dzp, t0);                                           \
        f32x2 u0 = pk_fma(pn12, dzp, pk_mul(pn11, dyp));                      \
        f32x2 arg = pk_fma(dzp, pk_mul(pn22, dzp),                            \
                           pk_fma(dyp, u0, pk_mul(dxp, t0)));                 \
        unsigned pbA = (unsigned)__builtin_amdgcn_readfirstlane(              \
                           (int)__float_as_uint(c_pb.S0));                    \
        unsigned pbB = (unsigned)__builtin_amdgcn_readfirstlane(              \
                           (int)__float_as_uint(c_pb.S1));                    \
        int bxA = (int)(pbA >> 16), byA = (int)((pbA >> 8) & 255u),           \
            bzA = (int)(pbA & 255u);                                          \
        int bxB = (int)(pbB >> 16), byB = (int)((pbB >> 8) & 255u),           \
            bzB = (int)(pbB & 255u);                                          \
        unsigned uxA = (unsigned)(vxp4 - bxA);                                \
        unsigned uyA = (unsigned)(vyp4 - byA);                                \
        unsigned uzA = (unsigned)(vzp4 - bzA);                                \
        bool inA = max(max(uxA, uyA), uzA) < 6u;                              \
        unsigned uxB = (unsigned)(vxp4 - bxB);                                \
        unsigned uyB = (unsigned)(vyp4 - byB);                                \
        unsigned uzB = (unsigned)(vzp4 - bzB);                                \
        bool inB = max(max(uxB, uyB), uzB) < 6u;                              \
        float wA = inA ? exp2f(arg.x) : 0.0f;                                 \
        float wB = inB ? exp2f(arg.y) : 0.0f;                                 \
        accR = fmaf(wA, c_wr.S0, fmaf(wB, c_wr.S1, accR));                    \
        accI = fmaf(wA, c_wi.S0, fmaf(wB, c_wi.S1, accI));                    \
    } while (0)

// ---------------- K2: fused candidate-pull + paired packed eval ------------
__global__ __launch_bounds__(256) void cgr_eval(
    const float* __restrict__ rec,
    const int* __restrict__ homecnt,
    const unsigned* __restrict__ hpb,
    const int* __restrict__ hlist,
    float* __restrict__ grid)
{
    __shared__ __align__(16) float sbuf[4][12 * 64];   // component-major recs
    __shared__ int idbuf[4][CAP];                      // candidate ids

    const float VOXC = 2.0f / 128.0f;

    int bid = blockIdx.x;
    int swz = (bid & 7) * 1024 + (bid >> 3);   // XCD-chunked swizzle

    int wave = threadIdx.x >> 6;
    int lane = threadIdx.x & 63;
    int s = swz * 4 + wave;                 // 0..NTILE-1
    int sx = s >> 10;
    int sy = (s >> 5) & 31;
    int sz = s & 31;
    int vx = sx * 4 + (lane >> 4);
    int vy = sy * 4 + ((lane >> 2) & 3);
    int vz = sz * 4 + (lane & 3);
    float fvx = (float)vx, fvy = (float)vy, fvz = (float)vz;
    int vxp4 = vx + 4, vyp4 = vy + 4, vzp4 = vz + 4;

    f32x2 fvx2 = {fvx, fvx}, fvy2 = {fvy, fvy}, fvz2 = {fvz, fvz};
    f32x2 voxc2 = {VOXC, VOXC};

    // base-window test constants: overlap iff pb_field - (4s-1) in [0,8]
    int x0 = 4 * sx - 1, y0 = 4 * sy - 1, z0 = 4 * sz - 1;

    // --- load 27 neighbor-home counts (lanes 0..26) ---
    int cnt_l = 0, hadr_l = 0;
    if (lane < 27) {
        int dx2 = lane / 9;
        int rem = lane - dx2 * 9;
        int dy2 = rem / 3;
        int dz2 = rem - dy2 * 3;
        int hx = sx + dx2 - 2, hy = sy + dy2 - 2, hz = sz + dz2 - 2;
        bool v = (hx >= 0) & (hy >= 0) & (hz >= 0);
        int hidx = v ? (hx * NSBA + hy) * NSBA + hz : 0;
        int c = homecnt[hidx];
        cnt_l  = v ? min(c, HCAP) : 0;
        hadr_l = hidx * HCAP;
    }

    int* idb = idbuf[wave];

    // --- scan slots: 9 iterations x (3 homes x 20 lanes); ballot-compact ---
    const int  grp  = lane / 20;            // 0..3 (lanes 60..63 idle)
    const int  slot = lane - grp * 20;
    const bool lv   = (grp < 3);
    int k = 0;
    #pragma unroll
    for (int it = 0; it < 9; ++it) {
        int hm   = lv ? (it * 3 + grp) : 0;
        int cnt  = __shfl(cnt_l, hm);
        int hadr = __shfl(hadr_l, hm);
        bool pass = lv & (slot < cnt);
        unsigned pb = 0u;
        int id = 0;
        if (pass) {
            pb = hpb[hadr + slot];
            id = hlist[hadr + slot];
        }
        if (pass) {
            pass = ((unsigned)((int)((pb >> 16) & 255u) - x0) <= 8u) &
                   ((unsigned)((int)((pb >> 8) & 255u)  - y0) <= 8u) &
                   ((unsigned)((int)(pb & 255u)         - z0) <= 8u);
        }
        unsigned long long mm = __ballot(pass);
        if (pass) {
            int pos = k + (int)__popcll(mm & ((1ull << lane) - 1ull));
            if (pos < CAP) idb[pos] = id;
        }
        k += (int)__popcll(mm);
    }
    int n = min(k, CAP);

    // --- stage (component-major) + paired packed evaluate ---
    float* sb = sbuf[wave];
    float accR = 0.0f, accI = 0.0f;

    for (int cs = 0; cs < n; cs += 64) {
        int m = min(64, n - cs);
        int mp4 = (m + 3) & ~3;             // pad to multiple of 4 candidates
        if (lane < m) {
            int id = idb[cs + lane];
            const float4* rp =
                reinterpret_cast<const float4*>(rec + (size_t)id * RECSZ);
            float4 v0 = rp[0], v1 = rp[1], v2 = rp[2];
            float* d = sb + lane;           // stride-64 per comp: conflict-free
            d[0*64]  = v0.x; d[1*64]  = v0.y;
            d[2*64]  = v0.z; d[3*64]  = v0.w;
            d[4*64]  = v1.x; d[5*64]  = v1.y;
            d[6*64]  = v1.z; d[7*64]  = v1.w;
            d[8*64]  = v2.x; d[9*64]  = v2.y;
            d[10*64] = v2.z; d[11*64] = v2.w;
        } else if (lane < mp4) {            // dummy: never in-footprint, w=0
            float* d = sb + lane;
            #pragma unroll
            for (int c = 0; c < 11; ++c) d[c * 64] = 0.0f;
            d[11 * 64] = __uint_as_float(0x00FFFFFFu);
        }
        // wave-private LDS: no barrier needed (per-wave program order)
        for (int t = 0; t < (mp4 >> 2); ++t) {
            const float* bp = sb + 4 * t;   // 4 candidates per iteration
            float4 c_n00 = *reinterpret_cast<const float4*>(bp + 0*64);
            float4 c_n01 = *reinterpret_cast<const float4*>(bp + 1*64);
            float4 c_n02 = *reinterpret_cast<const float4*>(bp + 2*64);
            float4 c_n11 = *reinterpret_cast<const float4*>(bp + 3*64);
            float4 c_n12 = *reinterpret_cast<const float4*>(bp + 4*64);
            float4 c_n22 = *reinterpret_cast<const float4*>(bp + 5*64);
            float4 c_fx  = *reinterpret_cast<const float4*>(bp + 6*64);
            float4 c_fy  = *reinterpret_cast<const float4*>(bp + 7*64);
            float4 c_fz  = *reinterpret_cast<const float4*>(bp + 8*64);
            float4 c_wr  = *reinterpret_cast<const float4*>(bp + 9*64);
            float4 c_wi  = *reinterpret_cast<const float4*>(bp + 10*64);
            float4 c_pb  = *reinterpret_cast<const float4*>(bp + 11*64);
            EVAL_PAIR(x, y);                // candidates 4t, 4t+1
            EVAL_PAIR(z, w);                // candidates 4t+2, 4t+3
        }
    }

    size_t addr = ((size_t)(vx * RES + vy) * RES + vz) * 2;
    *reinterpret_cast<float2*>(grid + addr) = make_float2(accR, accI);
}

extern "C" void kernel_launch(void* const* d_in, const int* in_sizes, int n_in,
                              void* d_out, int out_size, void* d_ws, size_t ws_size,
                              hipStream_t stream) {
    const float* means      = (const float*)d_in[0];
    const float* opacities  = (const float*)d_in[1];
    const float* scales     = (const float*)d_in[2];
    const float* rotations  = (const float*)d_in[3];
    const float* phases     = (const float*)d_in[4];
    const float* phases_add = (const float*)d_in[5];
    float* grid = (float*)d_out;

    int N = in_sizes[1];
    int nb = (N + 255) / 256;

    // ws layout (~10.2 MB)
    char* p = (char*)d_ws;
    float*    rec     = (float*)p;     p += (size_t)N * RECSZ * sizeof(float);
    int*      homecnt = (int*)p;       p += (size_t)NTILE * sizeof(int);
    unsigned* hpb     = (unsigned*)p;  p += (size_t)NTILE * HCAP * sizeof(unsigned);
    int*      hlist   = (int*)p;

    (void)hipMemsetAsync(homecnt, 0, (size_t)NTILE * sizeof(int), stream);
    cgr_build<<<nb, 256, 0, stream>>>(means, opacities, scales, rotations,
                                      phases, phases_add, rec, homecnt,
                                      hpb, hlist, N);
    cgr_eval<<<NTILE / 4, 256, 0, stream>>>(rec, homecnt, hpb, hlist, grid);
}

// Round 19
// 83.837 us; speedup vs baseline: 1.0900x; 1.0900x over previous
//
#include <hip/hip_runtime.h>
#include <math.h>

// ComplexGaussianRasterizer — home-bucket bin + fused pull-scan voxel-gather,
// candidate-pair packed eval, component-major LDS staging, RAW v_exp_f32.
// 3 nodes:
//   memset:  zero homecnt (128 KB).
//   K1 build: per gaussian -> 48B record at rec[g] (coalesced); append
//             (pb, id) to its 4^3 home cell's fixed-HCAP bucket (1 atomic).
//   K2 eval:  one wave per 4^3 subtile, one voxel per lane. Wave pulls the 27
//             neighbor homes' (pb,id) slots, window-tests, ballot-compacts ids
//             into wave-private LDS. Component-major staging (zero conflicts);
//             float4 read at c*64+4t serves 4 candidates. Pair quadratic via
//             v_pk_fma_f32; exp via raw v_exp_f32 (args <= 0; flush-to-zero
//             below 2^-126 is the desired w~0); in-test via readfirstlane +
//             SALU unpack.

#define RES    128
#define NSBA   32
#define NTILE  (NSBA * NSBA * NSBA)   // 32768 home cells
#define RECSZ  12                     // floats per record (48 B)
#define HCAP   20                     // home-bucket capacity (lambda ~3.05)
#define CAP    96                     // per-subtile candidate cap (lambda ~35)

typedef float f32x2 __attribute__((ext_vector_type(2)));

__device__ __forceinline__ f32x2 pk_fma(f32x2 a, f32x2 b, f32x2 c) {
    f32x2 d;
    asm("v_pk_fma_f32 %0, %1, %2, %3" : "=v"(d) : "v"(a), "v"(b), "v"(c));
    return d;
}
__device__ __forceinline__ f32x2 pk_mul(f32x2 a, f32x2 b) {
    f32x2 d;
    asm("v_pk_mul_f32 %0, %1, %2" : "=v"(d) : "v"(a), "v"(b));
    return d;
}
// raw 2^x: valid for x <= 0 (x < -126 flushes to 0, which is the wanted w~0).
// s_nop guards the trans-op result hazard (inline asm bypasses the hazard
// recognizer's automatic insertion).
__device__ __forceinline__ float fast_exp2(float x) {
    float r;
    asm("v_exp_f32 %0, %1\n\ts_nop 0" : "=v"(r) : "v"(x));
    return r;
}

// ---------------- record builder (quad coeffs scaled by log2e) -------------
__device__ __forceinline__ void build_record_at(
    const float* means, const float* opacities, const float* scales,
    const float* rotations, const float* phases, const float* phases_add,
    float* recdst, int g, int* bxo, int* byo, int* bzo)
{
    const float LB   = -1.0f;
    const float VOX  = 2.0f / 128.0f;
    const float L2E  = 1.4426950408889634f;

    float mx = means[g*3+0], my = means[g*3+1], mz = means[g*3+2];
    float op = opacities[g];
    float sx = scales[g*3+0], sy = scales[g*3+1], sz = scales[g*3+2];
    float qw = rotations[g*4+0], qx = rotations[g*4+1],
          qy = rotations[g*4+2], qz = rotations[g*4+3];
    float ph = phases[g], pa = phases_add[g];

    float qn = rsqrtf(qw*qw + qx*qx + qy*qy + qz*qz);
    qw *= qn; qx *= qn; qy *= qn; qz *= qn;

    float r00 = 1.0f - 2.0f*(qy*qy + qz*qz);
    float r01 = 2.0f*(qx*qy - qw*qz);
    float r02 = 2.0f*(qx*qz + qw*qy);
    float r10 = 2.0f*(qx*qy + qw*qz);
    float r11 = 1.0f - 2.0f*(qx*qx + qz*qz);
    float r12 = 2.0f*(qy*qz - qw*qx);
    float r20 = 2.0f*(qx*qz - qw*qy);
    float r21 = 2.0f*(qy*qz + qw*qx);
    float r22 = 1.0f - 2.0f*(qx*qx + qy*qy);

    float m00 = r00*sx, m01 = r01*sy, m02 = r02*sz;
    float m10 = r10*sx, m11 = r11*sy, m12 = r12*sz;
    float m20 = r20*sx, m21 = r21*sy, m22 = r22*sz;

    float a = m00*m00 + m01*m01 + m02*m02;
    float b = m00*m10 + m01*m11 + m02*m12;
    float c = m00*m20 + m01*m21 + m02*m22;
    float d = m10*m10 + m11*m11 + m12*m12;
    float e = m10*m20 + m11*m21 + m12*m22;
    float f = m20*m20 + m21*m21 + m22*m22;

    float A = d*f - e*e;
    float B = c*e - b*f;
    float C = b*e - c*d;
    float det  = a*A + b*B + c*C;
    float idet = L2E / det;            // fold log2e into all quad coeffs

    float n00 = -0.5f * A * idet;
    float n01 = -B * idet;
    float n02 = -C * idet;
    float n11 = -0.5f * (a*f - c*c) * idet;
    float n12 = -(b*c - a*e) * idet;
    float n22 = -0.5f * (a*d - b*b) * idet;

    int bx = (int)floorf((mx - LB) * 64.0f) - 3;
    int by = (int)floorf((my - LB) * 64.0f) - 3;
    int bz = (int)floorf((mz - LB) * 64.0f) - 3;
    unsigned pb = ((unsigned)(bx + 4) << 16) | ((unsigned)(by + 4) << 8) |
                  (unsigned)(bz + 4);

    float sr, cr;
    __sincosf(ph, &sr, &cr);
    float wr = op * cr;
    float wi = op * (sr + pa);

    float fx = LB + 0.5f * VOX - mx;
    float fy = LB + 0.5f * VOX - my;
    float fz = LB + 0.5f * VOX - mz;

    float4* rp = reinterpret_cast<float4*>(recdst);
    rp[0] = make_float4(n00, n01, n02, n11);
    rp[1] = make_float4(n12, n22, fx, fy);
    rp[2] = make_float4(fz, wr, wi, __uint_as_float(pb));
    *bxo = bx; *byo = by; *bzo = bz;
}

// ---------------- K1: build records + home-bucket append ----------------
__global__ __launch_bounds__(256) void cgr_build(
    const float* __restrict__ means, const float* __restrict__ opacities,
    const float* __restrict__ scales, const float* __restrict__ rotations,
    const float* __restrict__ phases, const float* __restrict__ phases_add,
    float* __restrict__ rec, int* __restrict__ homecnt,
    unsigned* __restrict__ hpb, int* __restrict__ hlist, int N)
{
    int g = blockIdx.x * 256 + threadIdx.x;
    if (g >= N) return;
    int bx, by, bz;
    build_record_at(means, opacities, scales, rotations, phases, phases_add,
                    rec + (size_t)g * RECSZ, g, &bx, &by, &bz);
    unsigned pb = ((unsigned)(bx + 4) << 16) | ((unsigned)(by + 4) << 8) |
                  (unsigned)(bz + 4);
    int hx = min(max(bx, 0), RES - 1) >> 2;
    int hy = min(max(by, 0), RES - 1) >> 2;
    int hz = min(max(bz, 0), RES - 1) >> 2;
    int h = (hx * NSBA + hy) * NSBA + hz;
    int slot = atomicAdd(&homecnt[h], 1);
    if (slot < HCAP) {
        hpb[h * HCAP + slot]   = pb;
        hlist[h * HCAP + slot] = g;
    }
}

// evaluate one candidate pair from component float4s (S0/S1 select the pair)
#define EVAL_PAIR(S0, S1)                                                     \
    do {                                                                      \
        f32x2 pn00 = {c_n00.S0, c_n00.S1};                                    \
        f32x2 pn01 = {c_n01.S0, c_n01.S1};                                    \
        f32x2 pn02 = {c_n02.S0, c_n02.S1};                                    \
        f32x2 pn11 = {c_n11.S0, c_n11.S1};                                    \
        f32x2 pn12 = {c_n12.S0, c_n12.S1};                                    \
        f32x2 pn22 = {c_n22.S0, c_n22.S1};                                    \
        f32x2 pfx  = {c_fx.S0,  c_fx.S1};                                     \
        f32x2 pfy  = {c_fy.S0,  c_fy.S1};                                     \
        f32x2 pfz  = {c_fz.S0,  c_fz.S1};                                     \
        f32x2 dxp = pk_fma(fvx2, voxc2, pfx);                                 \
        f32x2 dyp = pk_fma(fvy2, voxc2, pfy);                                 \
        f32x2 dzp = pk_fma(fvz2, voxc2, pfz);                                 \
        f32x2 t0 = pk_fma(pn01, dyp, pk_mul(pn00, dxp));                      \
        t0 = pk_fma(pn02, dzp, t0);                                           \
        f32x2 u0 = pk_fma(pn12, dzp, pk_mul(pn11, dyp));                      \
        f32x2 arg = pk_fma(dzp, pk_mul(pn22, dzp),                            \
                           pk_fma(dyp, u0, pk_mul(dxp, t0)));                 \
        unsigned pbA = (unsigned)__builtin_amdgcn_readfirstlane(              \
                           (int)__float_as_uint(c_pb.S0));                    \
        unsigned pbB = (unsigned)__builtin_amdgcn_readfirstlane(              \
                           (int)__float_as_uint(c_pb.S1));                    \
        int bxA = (int)(pbA >> 16), byA = (int)((pbA >> 8) & 255u),           \
            bzA = (int)(pbA & 255u);                                          \
        int bxB = (int)(pbB >> 16), byB = (int)((pbB >> 8) & 255u),           \
            bzB = (int)(pbB & 255u);                                          \
        unsigned uxA = (unsigned)(vxp4 - bxA);                                \
        unsigned uyA = (unsigned)(vyp4 - byA);                                \
        unsigned uzA = (unsigned)(vzp4 - bzA);                                \
        bool inA = max(max(uxA, uyA), uzA) < 6u;                              \
        unsigned uxB = (unsigned)(vxp4 - bxB);                                \
        unsigned uyB = (unsigned)(vyp4 - byB);                                \
        unsigned uzB = (unsigned)(vzp4 - bzB);                                \
        bool inB = max(max(uxB, uyB), uzB) < 6u;                              \
        float wA = inA ? fast_exp2(arg.x) : 0.0f;                             \
        float wB = inB ? fast_exp2(arg.y) : 0.0f;                             \
        accR = fmaf(wA, c_wr.S0, fmaf(wB, c_wr.S1, accR));                    \
        accI = fmaf(wA, c_wi.S0, fmaf(wB, c_wi.S1, accI));                    \
    } while (0)

// ---------------- K2: fused candidate-pull + paired packed eval ------------
__global__ __launch_bounds__(256) void cgr_eval(
    const float* __restrict__ rec,
    const int* __restrict__ homecnt,
    const unsigned* __restrict__ hpb,
    const int* __restrict__ hlist,
    float* __restrict__ grid)
{
    __shared__ __align__(16) float sbuf[4][12 * 64];   // component-major recs
    __shared__ int idbuf[4][CAP];                      // candidate ids

    const float VOXC = 2.0f / 128.0f;

    int bid = blockIdx.x;
    int swz = (bid & 7) * 1024 + (bid >> 3);   // XCD-chunked swizzle

    int wave = threadIdx.x >> 6;
    int lane = threadIdx.x & 63;
    int s = swz * 4 + wave;                 // 0..NTILE-1
    int sx = s >> 10;
    int sy = (s >> 5) & 31;
    int sz = s & 31;
    int vx = sx * 4 + (lane >> 4);
    int vy = sy * 4 + ((lane >> 2) & 3);
    int vz = sz * 4 + (lane & 3);
    float fvx = (float)vx, fvy = (float)vy, fvz = (float)vz;
    int vxp4 = vx + 4, vyp4 = vy + 4, vzp4 = vz + 4;

    f32x2 fvx2 = {fvx, fvx}, fvy2 = {fvy, fvy}, fvz2 = {fvz, fvz};
    f32x2 voxc2 = {VOXC, VOXC};

    // base-window test constants: overlap iff pb_field - (4s-1) in [0,8]
    int x0 = 4 * sx - 1, y0 = 4 * sy - 1, z0 = 4 * sz - 1;

    // --- load 27 neighbor-home counts (lanes 0..26) ---
    int cnt_l = 0, hadr_l = 0;
    if (lane < 27) {
        int dx2 = lane / 9;
        int rem = lane - dx2 * 9;
        int dy2 = rem / 3;
        int dz2 = rem - dy2 * 3;
        int hx = sx + dx2 - 2, hy = sy + dy2 - 2, hz = sz + dz2 - 2;
        bool v = (hx >= 0) & (hy >= 0) & (hz >= 0);
        int hidx = v ? (hx * NSBA + hy) * NSBA + hz : 0;
        int c = homecnt[hidx];
        cnt_l  = v ? min(c, HCAP) : 0;
        hadr_l = hidx * HCAP;
    }

    int* idb = idbuf[wave];

    // --- scan slots: 9 iterations x (3 homes x 20 lanes); ballot-compact ---
    const int  grp  = lane / 20;            // 0..3 (lanes 60..63 idle)
    const int  slot = lane - grp * 20;
    const bool lv   = (grp < 3);
    int k = 0;
    #pragma unroll
    for (int it = 0; it < 9; ++it) {
        int hm   = lv ? (it * 3 + grp) : 0;
        int cnt  = __shfl(cnt_l, hm);
        int hadr = __shfl(hadr_l, hm);
        bool pass = lv & (slot < cnt);
        unsigned pb = 0u;
        int id = 0;
        if (pass) {
            pb = hpb[hadr + slot];
            id = hlist[hadr + slot];
        }
        if (pass) {
            pass = ((unsigned)((int)((pb >> 16) & 255u) - x0) <= 8u) &
                   ((unsigned)((int)((pb >> 8) & 255u)  - y0) <= 8u) &
                   ((unsigned)((int)(pb & 255u)         - z0) <= 8u);
        }
        unsigned long long mm = __ballot(pass);
        if (pass) {
            int pos = k + (int)__popcll(mm & ((1ull << lane) - 1ull));
            if (pos < CAP) idb[pos] = id;
        }
        k += (int)__popcll(mm);
    }
    int n = min(k, CAP);

    // --- stage (component-major) + paired packed evaluate ---
    float* sb = sbuf[wave];
    float accR = 0.0f, accI = 0.0f;

    for (int cs = 0; cs < n; cs += 64) {
        int m = min(64, n - cs);
        int mp4 = (m + 3) & ~3;             // pad to multiple of 4 candidates
        if (lane < m) {
            int id = idb[cs + lane];
            const float4* rp =
                reinterpret_cast<const float4*>(rec + (size_t)id * RECSZ);
            float4 v0 = rp[0], v1 = rp[1], v2 = rp[2];
            float* d = sb + lane;           // stride-64 per comp: conflict-free
            d[0*64]  = v0.x; d[1*64]  = v0.y;
            d[2*64]  = v0.z; d[3*64]  = v0.w;
            d[4*64]  = v1.x; d[5*64]  = v1.y;
            d[6*64]  = v1.z; d[7*64]  = v1.w;
            d[8*64]  = v2.x; d[9*64]  = v2.y;
            d[10*64] = v2.z; d[11*64] = v2.w;
        } else if (lane < mp4) {            // dummy: never in-footprint, w=0
            float* d = sb + lane;
            #pragma unroll
            for (int c = 0; c < 11; ++c) d[c * 64] = 0.0f;
            d[11 * 64] = __uint_as_float(0x00FFFFFFu);
        }
        // wave-private LDS: no barrier needed (per-wave program order)
        for (int t = 0; t < (mp4 >> 2); ++t) {
            const float* bp = sb + 4 * t;   // 4 candidates per iteration
            float4 c_n00 = *reinterpret_cast<const float4*>(bp + 0*64);
            float4 c_n01 = *reinterpret_cast<const float4*>(bp + 1*64);
            float4 c_n02 = *reinterpret_cast<const float4*>(bp + 2*64);
            float4 c_n11 = *reinterpret_cast<const float4*>(bp + 3*64);
            float4 c_n12 = *reinterpret_cast<const float4*>(bp + 4*64);
            float4 c_n22 = *reinterpret_cast<const float4*>(bp + 5*64);
            float4 c_fx  = *reinterpret_cast<const float4*>(bp + 6*64);
            float4 c_fy  = *reinterpret_cast<const float4*>(bp + 7*64);
            float4 c_fz  = *reinterpret_cast<const float4*>(bp + 8*64);
            float4 c_wr  = *reinterpret_cast<const float4*>(bp + 9*64);
            float4 c_wi  = *reinterpret_cast<const float4*>(bp + 10*64);
            float4 c_pb  = *reinterpret_cast<const float4*>(bp + 11*64);
            EVAL_PAIR(x, y);                // candidates 4t, 4t+1
            EVAL_PAIR(z, w);                // candidates 4t+2, 4t+3
        }
    }

    size_t addr = ((size_t)(vx * RES + vy) * RES + vz) * 2;
    *reinterpret_cast<float2*>(grid + addr) = make_float2(accR, accI);
}

extern "C" void kernel_launch(void* const* d_in, const int* in_sizes, int n_in,
                              void* d_out, int out_size, void* d_ws, size_t ws_size,
                              hipStream_t stream) {
    const float* means      = (const float*)d_in[0];
    const float* opacities  = (const float*)d_in[1];
    const float* scales     = (const float*)d_in[2];
    const float* rotations  = (const float*)d_in[3];
    const float* phases     = (const float*)d_in[4];
    const float* phases_add = (const float*)d_in[5];
    float* grid = (float*)d_out;

    int N = in_sizes[1];
    int nb = (N + 255) / 256;

    // ws layout (~10.2 MB)
    char* p = (char*)d_ws;
    float*    rec     = (float*)p;     p += (size_t)N * RECSZ * sizeof(float);
    int*      homecnt = (int*)p;       p += (size_t)NTILE * sizeof(int);
    unsigned* hpb     = (unsigned*)p;  p += (size_t)NTILE * HCAP * sizeof(unsigned);
    int*      hlist   = (int*)p;

    (void)hipMemsetAsync(homecnt, 0, (size_t)NTILE * sizeof(int), stream);
    cgr_build<<<nb, 256, 0, stream>>>(means, opacities, scales, rotations,
                                      phases, phases_add, rec, homecnt,
                                      hpb, hlist, N);
    cgr_eval<<<NTILE / 4, 256, 0, stream>>>(rec, homecnt, hpb, hlist, grid);
}

// Round 20
// 82.762 us; speedup vs baseline: 1.1042x; 1.0130x over previous
//
#include <hip/hip_runtime.h>
#include <math.h>

// ComplexGaussianRasterizer — home-bucket bin + fused pull-scan voxel-gather,
// PAIR-INTERLEAVED component staging: each ds_read_b128 yields two ready
// f32x2 operands (zero marshaling). Raw v_exp_f32, v_pk_fma quadratic.
// 3 nodes:
//   memset:  zero homecnt (128 KB).
//   K1 build: per gaussian -> 48B record at rec[g] (coalesced); append
//             (pb, id) to its 4^3 home cell's fixed-HCAP bucket (1 atomic).
//   K2 eval:  one wave per 4^3 subtile, one voxel per lane. Pull 27 neighbor
//             homes' (pb,id), window-test, ballot-compact ids to LDS. Stage
//             records as sb[(j>>1)*28 + c*2 + (j&1)] (pair stride 112B,
//             16B-aligned); eval loop: 6 uniform ds_read_b128 per pair ->
//             9 pre-packed f32x2 + wr/wi/pb pairs; v_pk_fma_f32 quadratic,
//             readfirstlane+SALU in-test, raw v_exp_f32, scalar accumulate.

#define RES    128
#define NSBA   32
#define NTILE  (NSBA * NSBA * NSBA)   // 32768 home cells
#define RECSZ  12                     // floats per record (48 B)
#define HCAP   20                     // home-bucket capacity (lambda ~3.05)
#define CAP    96                     // per-subtile candidate cap (lambda ~35)
#define PSTR   28                     // floats per pair slot (24 used + 4 pad)

typedef float f32x2 __attribute__((ext_vector_type(2)));

__device__ __forceinline__ f32x2 pk_fma(f32x2 a, f32x2 b, f32x2 c) {
    f32x2 d;
    asm("v_pk_fma_f32 %0, %1, %2, %3" : "=v"(d) : "v"(a), "v"(b), "v"(c));
    return d;
}
__device__ __forceinline__ f32x2 pk_mul(f32x2 a, f32x2 b) {
    f32x2 d;
    asm("v_pk_mul_f32 %0, %1, %2" : "=v"(d) : "v"(a), "v"(b));
    return d;
}
// raw 2^x: valid for x <= 0 (x < -126 flushes to 0 = wanted w~0).
__device__ __forceinline__ float fast_exp2(float x) {
    float r;
    asm("v_exp_f32 %0, %1\n\ts_nop 0" : "=v"(r) : "v"(x));
    return r;
}

// ---------------- record builder (quad coeffs scaled by log2e) -------------
__device__ __forceinline__ void build_record_at(
    const float* means, const float* opacities, const float* scales,
    const float* rotations, const float* phases, const float* phases_add,
    float* recdst, int g, int* bxo, int* byo, int* bzo)
{
    const float LB   = -1.0f;
    const float VOX  = 2.0f / 128.0f;
    const float L2E  = 1.4426950408889634f;

    float mx = means[g*3+0], my = means[g*3+1], mz = means[g*3+2];
    float op = opacities[g];
    float sx = scales[g*3+0], sy = scales[g*3+1], sz = scales[g*3+2];
    float qw = rotations[g*4+0], qx = rotations[g*4+1],
          qy = rotations[g*4+2], qz = rotations[g*4+3];
    float ph = phases[g], pa = phases_add[g];

    float qn = rsqrtf(qw*qw + qx*qx + qy*qy + qz*qz);
    qw *= qn; qx *= qn; qy *= qn; qz *= qn;

    float r00 = 1.0f - 2.0f*(qy*qy + qz*qz);
    float r01 = 2.0f*(qx*qy - qw*qz);
    float r02 = 2.0f*(qx*qz + qw*qy);
    float r10 = 2.0f*(qx*qy + qw*qz);
    float r11 = 1.0f - 2.0f*(qx*qx + qz*qz);
    float r12 = 2.0f*(qy*qz - qw*qx);
    float r20 = 2.0f*(qx*qz - qw*qy);
    float r21 = 2.0f*(qy*qz + qw*qx);
    float r22 = 1.0f - 2.0f*(qx*qx + qy*qy);

    float m00 = r00*sx, m01 = r01*sy, m02 = r02*sz;
    float m10 = r10*sx, m11 = r11*sy, m12 = r12*sz;
    float m20 = r20*sx, m21 = r21*sy, m22 = r22*sz;

    float a = m00*m00 + m01*m01 + m02*m02;
    float b = m00*m10 + m01*m11 + m02*m12;
    float c = m00*m20 + m01*m21 + m02*m22;
    float d = m10*m10 + m11*m11 + m12*m12;
    float e = m10*m20 + m11*m21 + m12*m22;
    float f = m20*m20 + m21*m21 + m22*m22;

    float A = d*f - e*e;
    float B = c*e - b*f;
    float C = b*e - c*d;
    float det  = a*A + b*B + c*C;
    float idet = L2E / det;            // fold log2e into all quad coeffs

    float n00 = -0.5f * A * idet;
    float n01 = -B * idet;
    float n02 = -C * idet;
    float n11 = -0.5f * (a*f - c*c) * idet;
    float n12 = -(b*c - a*e) * idet;
    float n22 = -0.5f * (a*d - b*b) * idet;

    int bx = (int)floorf((mx - LB) * 64.0f) - 3;
    int by = (int)floorf((my - LB) * 64.0f) - 3;
    int bz = (int)floorf((mz - LB) * 64.0f) - 3;
    unsigned pb = ((unsigned)(bx + 4) << 16) | ((unsigned)(by + 4) << 8) |
                  (unsigned)(bz + 4);

    float sr, cr;
    __sincosf(ph, &sr, &cr);
    float wr = op * cr;
    float wi = op * (sr + pa);

    float fx = LB + 0.5f * VOX - mx;
    float fy = LB + 0.5f * VOX - my;
    float fz = LB + 0.5f * VOX - mz;

    float4* rp = reinterpret_cast<float4*>(recdst);
    rp[0] = make_float4(n00, n01, n02, n11);
    rp[1] = make_float4(n12, n22, fx, fy);
    rp[2] = make_float4(fz, wr, wi, __uint_as_float(pb));
    *bxo = bx; *byo = by; *bzo = bz;
}

// ---------------- K1: build records + home-bucket append ----------------
__global__ __launch_bounds__(256) void cgr_build(
    const float* __restrict__ means, const float* __restrict__ opacities,
    const float* __restrict__ scales, const float* __restrict__ rotations,
    const float* __restrict__ phases, const float* __restrict__ phases_add,
    float* __restrict__ rec, int* __restrict__ homecnt,
    unsigned* __restrict__ hpb, int* __restrict__ hlist, int N)
{
    int g = blockIdx.x * 256 + threadIdx.x;
    if (g >= N) return;
    int bx, by, bz;
    build_record_at(means, opacities, scales, rotations, phases, phases_add,
                    rec + (size_t)g * RECSZ, g, &bx, &by, &bz);
    unsigned pb = ((unsigned)(bx + 4) << 16) | ((unsigned)(by + 4) << 8) |
                  (unsigned)(bz + 4);
    int hx = min(max(bx, 0), RES - 1) >> 2;
    int hy = min(max(by, 0), RES - 1) >> 2;
    int hz = min(max(bz, 0), RES - 1) >> 2;
    int h = (hx * NSBA + hy) * NSBA + hz;
    int slot = atomicAdd(&homecnt[h], 1);
    if (slot < HCAP) {
        hpb[h * HCAP + slot]   = pb;
        hlist[h * HCAP + slot] = g;
    }
}

// ---------------- K2: fused candidate-pull + pair-interleaved eval ---------
__global__ __launch_bounds__(256) void cgr_eval(
    const float* __restrict__ rec,
    const int* __restrict__ homecnt,
    const unsigned* __restrict__ hpb,
    const int* __restrict__ hlist,
    float* __restrict__ grid)
{
    __shared__ __align__(16) float sbuf[4][32 * PSTR]; // pair-interleaved recs
    __shared__ int idbuf[4][CAP];                      // candidate ids

    const float VOXC = 2.0f / 128.0f;

    int bid = blockIdx.x;
    int swz = (bid & 7) * 1024 + (bid >> 3);   // XCD-chunked swizzle

    int wave = threadIdx.x >> 6;
    int lane = threadIdx.x & 63;
    int s = swz * 4 + wave;                 // 0..NTILE-1
    int sx = s >> 10;
    int sy = (s >> 5) & 31;
    int sz = s & 31;
    int vx = sx * 4 + (lane >> 4);
    int vy = sy * 4 + ((lane >> 2) & 3);
    int vz = sz * 4 + (lane & 3);
    float fvx = (float)vx, fvy = (float)vy, fvz = (float)vz;
    int vxp4 = vx + 4, vyp4 = vy + 4, vzp4 = vz + 4;

    f32x2 fvx2 = {fvx, fvx}, fvy2 = {fvy, fvy}, fvz2 = {fvz, fvz};
    f32x2 voxc2 = {VOXC, VOXC};

    // base-window test constants: overlap iff pb_field - (4s-1) in [0,8]
    int x0 = 4 * sx - 1, y0 = 4 * sy - 1, z0 = 4 * sz - 1;

    // --- load 27 neighbor-home counts (lanes 0..26) ---
    int cnt_l = 0, hadr_l = 0;
    if (lane < 27) {
        int dx2 = lane / 9;
        int rem = lane - dx2 * 9;
        int dy2 = rem / 3;
        int dz2 = rem - dy2 * 3;
        int hx = sx + dx2 - 2, hy = sy + dy2 - 2, hz = sz + dz2 - 2;
        bool v = (hx >= 0) & (hy >= 0) & (hz >= 0);
        int hidx = v ? (hx * NSBA + hy) * NSBA + hz : 0;
        int c = homecnt[hidx];
        cnt_l  = v ? min(c, HCAP) : 0;
        hadr_l = hidx * HCAP;
    }

    int* idb = idbuf[wave];

    // --- scan slots: 9 iterations x (3 homes x 20 lanes); ballot-compact ---
    const int  grp  = lane / 20;            // 0..3 (lanes 60..63 idle)
    const int  slot = lane - grp * 20;
    const bool lv   = (grp < 3);
    int k = 0;
    #pragma unroll
    for (int it = 0; it < 9; ++it) {
        int hm   = lv ? (it * 3 + grp) : 0;
        int cnt  = __shfl(cnt_l, hm);
        int hadr = __shfl(hadr_l, hm);
        bool pass = lv & (slot < cnt);
        unsigned pb = 0u;
        int id = 0;
        if (pass) {
            pb = hpb[hadr + slot];
            id = hlist[hadr + slot];
        }
        if (pass) {
            pass = ((unsigned)((int)((pb >> 16) & 255u) - x0) <= 8u) &
                   ((unsigned)((int)((pb >> 8) & 255u)  - y0) <= 8u) &
                   ((unsigned)((int)(pb & 255u)         - z0) <= 8u);
        }
        unsigned long long mm = __ballot(pass);
        if (pass) {
            int pos = k + (int)__popcll(mm & ((1ull << lane) - 1ull));
            if (pos < CAP) idb[pos] = id;
        }
        k += (int)__popcll(mm);
    }
    int n = min(k, CAP);

    // --- stage (pair-interleaved comp-pairs) + packed evaluate ---
    float* sb = sbuf[wave];
    float accR = 0.0f, accI = 0.0f;

    for (int cs = 0; cs < n; cs += 64) {
        int m = min(64, n - cs);
        int me = (m + 1) & ~1;              // pad to even (dummy candidate)
        if (lane < m) {
            int id = idb[cs + lane];
            const float4* rp =
                reinterpret_cast<const float4*>(rec + (size_t)id * RECSZ);
            float4 v0 = rp[0], v1 = rp[1], v2 = rp[2];
            // comp c of cand j -> sb[(j>>1)*PSTR + 2c + (j&1)]
            float* d = sb + (lane >> 1) * PSTR + (lane & 1);
            d[0]  = v0.x; d[2]  = v0.y; d[4]  = v0.z; d[6]  = v0.w;
            d[8]  = v1.x; d[10] = v1.y; d[12] = v1.z; d[14] = v1.w;
            d[16] = v2.x; d[18] = v2.y; d[20] = v2.z; d[22] = v2.w;
        } else if (lane < me) {             // dummy: never in-footprint, w=0
            float* d = sb + (lane >> 1) * PSTR + (lane & 1);
            #pragma unroll
            for (int c = 0; c < 11; ++c) d[c * 2] = 0.0f;
            d[22] = __uint_as_float(0x00FFFFFFu);
        }
        // wave-private LDS: no barrier needed (per-wave program order)
        for (int pr = 0; pr < (me >> 1); ++pr) {
            const float4* q =
                reinterpret_cast<const float4*>(sb + pr * PSTR);
            float4 q0 = q[0];   // {n00_0,n00_1, n01_0,n01_1}
            float4 q1 = q[1];   // {n02 pair, n11 pair}
            float4 q2 = q[2];   // {n12 pair, n22 pair}
            float4 q3 = q[3];   // {fx pair, fy pair}
            float4 q4 = q[4];   // {fz pair, wr pair}
            float4 q5 = q[5];   // {wi pair, pb pair}

            f32x2 pn00 = {q0.x, q0.y}, pn01 = {q0.z, q0.w};
            f32x2 pn02 = {q1.x, q1.y}, pn11 = {q1.z, q1.w};
            f32x2 pn12 = {q2.x, q2.y}, pn22 = {q2.z, q2.w};
            f32x2 pfx  = {q3.x, q3.y}, pfy  = {q3.z, q3.w};
            f32x2 pfz  = {q4.x, q4.y};

            f32x2 dxp = pk_fma(fvx2, voxc2, pfx);
            f32x2 dyp = pk_fma(fvy2, voxc2, pfy);
            f32x2 dzp = pk_fma(fvz2, voxc2, pfz);
            f32x2 t0 = pk_fma(pn01, dyp, pk_mul(pn00, dxp));
            t0 = pk_fma(pn02, dzp, t0);
            f32x2 u0 = pk_fma(pn12, dzp, pk_mul(pn11, dyp));
            f32x2 arg = pk_fma(dzp, pk_mul(pn22, dzp),
                               pk_fma(dyp, u0, pk_mul(dxp, t0)));

            unsigned pbA = (unsigned)__builtin_amdgcn_readfirstlane(
                               (int)__float_as_uint(q5.z));
            unsigned pbB = (unsigned)__builtin_amdgcn_readfirstlane(
                               (int)__float_as_uint(q5.w));
            unsigned uxA = (unsigned)(vxp4 - (int)(pbA >> 16));
            unsigned uyA = (unsigned)(vyp4 - (int)((pbA >> 8) & 255u));
            unsigned uzA = (unsigned)(vzp4 - (int)(pbA & 255u));
            bool inA = max(max(uxA, uyA), uzA) < 6u;
            unsigned uxB = (unsigned)(vxp4 - (int)(pbB >> 16));
            unsigned uyB = (unsigned)(vyp4 - (int)((pbB >> 8) & 255u));
            unsigned uzB = (unsigned)(vzp4 - (int)(pbB & 255u));
            bool inB = max(max(uxB, uyB), uzB) < 6u;

            float wA = inA ? fast_exp2(arg.x) : 0.0f;
            float wB = inB ? fast_exp2(arg.y) : 0.0f;
            accR = fmaf(wA, q4.z, fmaf(wB, q4.w, accR));
            accI = fmaf(wA, q5.x, fmaf(wB, q5.y, accI));
        }
    }

    size_t addr = ((size_t)(vx * RES + vy) * RES + vz) * 2;
    *reinterpret_cast<float2*>(grid + addr) = make_float2(accR, accI);
}

extern "C" void kernel_launch(void* const* d_in, const int* in_sizes, int n_in,
                              void* d_out, int out_size, void* d_ws, size_t ws_size,
                              hipStream_t stream) {
    const float* means      = (const float*)d_in[0];
    const float* opacities  = (const float*)d_in[1];
    const float* scales     = (const float*)d_in[2];
    const float* rotations  = (const float*)d_in[3];
    const float* phases     = (const float*)d_in[4];
    const float* phases_add = (const float*)d_in[5];
    float* grid = (float*)d_out;

    int N = in_sizes[1];
    int nb = (N + 255) / 256;

    // ws layout (~10.2 MB)
    char* p = (char*)d_ws;
    float*    rec     = (float*)p;     p += (size_t)N * RECSZ * sizeof(float);
    int*      homecnt = (int*)p;       p += (size_t)NTILE * sizeof(int);
    unsigned* hpb     = (unsigned*)p;  p += (size_t)NTILE * HCAP * sizeof(unsigned);
    int*      hlist   = (int*)p;

    (void)hipMemsetAsync(homecnt, 0, (size_t)NTILE * sizeof(int), stream);
    cgr_build<<<nb, 256, 0, stream>>>(means, opacities, scales, rotations,
                                      phases, phases_add, rec, homecnt,
                                      hpb, hlist, N);
    cgr_eval<<<NTILE / 4, 256, 0, stream>>>(rec, homecnt, hpb, hlist, grid);
}